// Round 9
// baseline (299.659 us; speedup 1.0000x reference)
//
#include <hip/hip_runtime.h>

#define WG 256
#define BN 128        // nodes per bucket
#define NBMAX 800     // max buckets (N <= 102400)
#define CHUNK 4096    // edges per binning chunk

typedef unsigned int uint32;

__device__ inline ushort f2bf(float f) {  // fp32 -> bf16 RNE
  uint32 u = __float_as_uint(f);
  return (ushort)((u + 0x7fffu + ((u >> 16) & 1u)) >> 16);
}
__device__ inline float bflo(uint32 v) { return __uint_as_float(v << 16); }
__device__ inline float bfhi(uint32 v) { return __uint_as_float(v & 0xffff0000u); }

// int64 layout <=> all odd 32-bit words of the first 8 entries are zero.
__device__ inline bool detect_i64(const uint32* ei) {
  uint32 acc = 0;
#pragma unroll
  for (int i = 0; i < 8; i++) acc |= ei[2 * i + 1];
  return acc == 0u;
}

// ---------------------------------------------------------------------------
// Single-pass binning: per-chunk LDS histogram -> one global atomicAdd per
// (chunk,bucket) reserves a slice in [b*CAP,(b+1)*CAP) -> scatter packed
// (src<<7 | dst%BN). cursor[] pre-zeroed; afterwards cursor[b] = bucket count.
// uint4-vectorized edge loads on full chunks (2 edges/load for i64 layout,
// 4 for i32); scalar fallback for the partial tail chunk / odd alignment.
// ---------------------------------------------------------------------------
__global__ __launch_bounds__(WG) void k_bin(const int* __restrict__ ei,
                                            int* __restrict__ cursor,
                                            uint32* __restrict__ pairs,
                                            int NB, int E, int CAP) {
  __shared__ int hc[NBMAX];
  __shared__ int curs[NBMAX];
  const int c = blockIdx.x;
  const int t = threadIdx.x;
  for (int b = t; b < NB; b += WG) hc[b] = 0;
  __syncthreads();
  const bool i64 = detect_i64((const uint32*)ei);
  const uint32* eu = (const uint32*)ei;
  const int e0 = c * CHUNK;
  const bool full = (e0 + CHUNK <= E);

  // ---- pass 1: histogram ----
  if (full && i64 && ((E & 1) == 0)) {
    const uint4* dq = (const uint4*)(eu + 2 * (size_t)E + 2 * (size_t)e0);
    for (int i = t; i < CHUNK / 2; i += WG) {
      uint4 v = dq[i];
      atomicAdd(&hc[v.x / BN], 1);
      atomicAdd(&hc[v.z / BN], 1);
    }
  } else if (full && !i64 && ((E & 3) == 0)) {
    const uint4* dq = (const uint4*)(eu + (size_t)E + e0);
    for (int i = t; i < CHUNK / 4; i += WG) {
      uint4 v = dq[i];
      atomicAdd(&hc[v.x / BN], 1);
      atomicAdd(&hc[v.y / BN], 1);
      atomicAdd(&hc[v.z / BN], 1);
      atomicAdd(&hc[v.w / BN], 1);
    }
  } else {
    for (int i = 0; i < CHUNK; i += WG) {
      int e = e0 + i + t;
      if (e < E) {
        int d = i64 ? ei[2 * (E + (size_t)e)] : ei[E + (size_t)e];
        atomicAdd(&hc[d / BN], 1);
      }
    }
  }
  __syncthreads();

  // ---- reserve slices ----
  for (int b = t; b < NB; b += WG) {
    int cnt = hc[b];
    int base = 0;
    if (cnt > 0) base = atomicAdd(&cursor[b], cnt);
    curs[b] = b * CAP + base;
  }
  __syncthreads();

  // ---- pass 2: scatter ----
  if (full && i64 && ((E & 1) == 0)) {
    const uint4* sq = (const uint4*)(eu + 2 * (size_t)e0);
    const uint4* dq = (const uint4*)(eu + 2 * (size_t)E + 2 * (size_t)e0);
    for (int i = t; i < CHUNK / 2; i += WG) {
      uint4 sv = sq[i], dv = dq[i];
      int b0 = dv.x / BN;
      int p0 = atomicAdd(&curs[b0], 1);
      if (p0 < (b0 + 1) * CAP) pairs[p0] = (sv.x << 7) | (dv.x & (BN - 1));
      int b1 = dv.z / BN;
      int p1 = atomicAdd(&curs[b1], 1);
      if (p1 < (b1 + 1) * CAP) pairs[p1] = (sv.z << 7) | (dv.z & (BN - 1));
    }
  } else if (full && !i64 && ((E & 3) == 0)) {
    const uint4* sq = (const uint4*)(eu + e0);
    const uint4* dq = (const uint4*)(eu + (size_t)E + e0);
    for (int i = t; i < CHUNK / 4; i += WG) {
      uint4 sv = sq[i], dv = dq[i];
      uint32 ss[4] = {sv.x, sv.y, sv.z, sv.w};
      uint32 dd[4] = {dv.x, dv.y, dv.z, dv.w};
#pragma unroll
      for (int u = 0; u < 4; u++) {
        int b = dd[u] / BN;
        int pos = atomicAdd(&curs[b], 1);
        if (pos < (b + 1) * CAP) pairs[pos] = (ss[u] << 7) | (dd[u] & (BN - 1));
      }
    }
  } else {
    for (int i = 0; i < CHUNK; i += WG) {
      int e = e0 + i + t;
      if (e < E) {
        int s, d;
        if (i64) { s = ei[2 * (size_t)e]; d = ei[2 * (E + (size_t)e)]; }
        else     { s = ei[e];             d = ei[E + (size_t)e]; }
        int b = d / BN;
        int pos = atomicAdd(&curs[b], 1);
        if (pos < (b + 1) * CAP)
          pairs[pos] = ((uint32)s << 7) | (uint32)(d & (BN - 1));
      }
    }
  }
}

// ---------------------------------------------------------------------------
// Per-bucket counting sort: packed pairs -> perm (grouped per dst node),
// rowbeg/rowend, dinv. Cursors in LDS; writes contiguous per block.
// ---------------------------------------------------------------------------
__global__ __launch_bounds__(WG) void k_bsort(const uint32* __restrict__ pairs,
                                              const int* __restrict__ cursor,
                                              int* __restrict__ perm,
                                              int* __restrict__ rowbeg,
                                              int* __restrict__ rowend,
                                              float* __restrict__ dinv,
                                              int N, int CAP) {
  __shared__ int cnt[BN];
  __shared__ int cur[BN];
  __shared__ int sc[BN];
  const int b = blockIdx.x;
  const int t = threadIdx.x;
  if (t < BN) cnt[t] = 0;
  __syncthreads();
  const int beg = b * CAP;
  int cb = cursor[b];
  const int end = beg + (cb < CAP ? cb : CAP);
  for (int e = beg + t; e < end; e += WG)
    atomicAdd(&cnt[pairs[e] & (BN - 1)], 1);
  __syncthreads();
  if (t < BN) sc[t] = cnt[t];
  __syncthreads();
  for (int off = 1; off < BN; off <<= 1) {
    int v = (t < BN && t >= off) ? sc[t - off] : 0;
    __syncthreads();
    if (t < BN) sc[t] += v;
    __syncthreads();
  }
  if (t < BN) {
    int excl = beg + sc[t] - cnt[t];
    cur[t] = excl;
    int n = b * BN + t;
    if (n < N) {
      rowbeg[n] = excl;
      rowend[n] = excl + cnt[t];
      dinv[n] = rsqrtf((float)(cnt[t] + 1));  // +1 = self-loop
    }
  }
  __syncthreads();
  for (int e = beg + t; e < end; e += WG) {
    uint32 p = pairs[e];
    int pos = atomicAdd(&cur[p & (BN - 1)], 1);
    perm[pos] = (int)(p >> 7);
  }
}

// ---------------------------------------------------------------------------
// GEMM1: ht1[n][64] = bf16( (x[n][128] @ W1[128][64]) * dinv[n] )
// ---------------------------------------------------------------------------
__global__ __launch_bounds__(WG) void k_gemm1(const float* __restrict__ x,
                                              const float* __restrict__ W1,
                                              const float* __restrict__ dinv,
                                              uint32* __restrict__ ht1, int N) {
  __shared__ float xs[64 * 128];
  __shared__ float w1s[128 * 64];
  const int tid = threadIdx.x;
  const int n0 = blockIdx.x * 64;

  for (int v = tid; v < 2048; v += WG)
    *(float4*)&w1s[v * 4] = ((const float4*)W1)[v];
  for (int v = tid; v < 2048; v += WG) {
    int row = v >> 5, c4 = v & 31;
    int n = n0 + row;
    float4 val = make_float4(0.f, 0.f, 0.f, 0.f);
    if (n < N) val = ((const float4*)x)[(size_t)n * 32 + c4];
    *(float4*)&xs[row * 128 + ((c4 ^ ((row >> 2) & 3)) << 2)] = val;
  }
  __syncthreads();

  const int cg = tid & 15;
  const int ng = tid >> 4;
  const int ngm = ng & 3;
  float acc[4][4] = {};

#pragma unroll 4
  for (int k4 = 0; k4 < 32; k4++) {
    float4 xa[4], wv[4];
#pragma unroll
    for (int i = 0; i < 4; i++)
      xa[i] = *(const float4*)&xs[(ng * 4 + i) * 128 + ((k4 ^ ngm) << 2)];
#pragma unroll
    for (int kk = 0; kk < 4; kk++)
      wv[kk] = *(const float4*)&w1s[(k4 * 4 + kk) * 64 + cg * 4];
#pragma unroll
    for (int i = 0; i < 4; i++) {
#pragma unroll
      for (int kk = 0; kk < 4; kk++) {
        float a = (kk == 0) ? xa[i].x : (kk == 1) ? xa[i].y : (kk == 2) ? xa[i].z : xa[i].w;
        acc[i][0] += a * wv[kk].x;
        acc[i][1] += a * wv[kk].y;
        acc[i][2] += a * wv[kk].z;
        acc[i][3] += a * wv[kk].w;
      }
    }
  }

#pragma unroll
  for (int i = 0; i < 4; i++) {
    int n = n0 + ng * 4 + i;
    if (n >= N) continue;
    float dv = dinv[n];
    uint32 u01 = ((uint32)f2bf(acc[i][1] * dv) << 16) | f2bf(acc[i][0] * dv);
    uint32 u23 = ((uint32)f2bf(acc[i][3] * dv) << 16) | f2bf(acc[i][2] * dv);
    ((uint2*)ht1)[(size_t)n * 16 + cg] = make_uint2(u01, u23);
  }
}

// ---------------------------------------------------------------------------
// CSR aggregation, 64 ch bf16: wave per node; 4 edge slots x uint2 lanes;
// 32-edge deep unroll (8 perm + 8 table loads in flight); perm loads
// non-temporal (stream) to preserve L2 for the gather table; fp32 accum.
// ---------------------------------------------------------------------------
__global__ __launch_bounds__(WG) void k_agg64b(const int* __restrict__ rowbeg,
                                               const int* __restrict__ rowend,
                                               const int* __restrict__ perm,
                                               const float* __restrict__ dinv,
                                               const uint32* __restrict__ ht,
                                               float* __restrict__ agg, int N) {
  int n = (blockIdx.x * WG + threadIdx.x) >> 6;
  int lane = threadIdx.x & 63;
  if (n >= N) return;
  const int sub = lane >> 4;   // edge slot 0..3
  const int cp = lane & 15;    // uint2 index within 128B row
  const uint2* __restrict__ tab = (const uint2*)ht;
  int beg = rowbeg[n], end = rowend[n];
  float a0 = 0.f, a1 = 0.f, a2 = 0.f, a3 = 0.f;
  if (sub == 0) {  // self-loop term
    uint2 v = tab[(size_t)n * 16 + cp];
    a0 += bflo(v.x); a1 += bfhi(v.x); a2 += bflo(v.y); a3 += bfhi(v.y);
  }
  int j = beg;
  for (; j + 32 <= end; j += 32) {  // 32 edges per iteration
    int s[8];
    uint2 v[8];
#pragma unroll
    for (int u = 0; u < 8; u++)
      s[u] = __builtin_nontemporal_load(&perm[j + 4 * u + sub]);
#pragma unroll
    for (int u = 0; u < 8; u++) v[u] = tab[(size_t)s[u] * 16 + cp];
#pragma unroll
    for (int u = 0; u < 8; u++) {
      a0 += bflo(v[u].x); a1 += bfhi(v[u].x);
      a2 += bflo(v[u].y); a3 += bfhi(v[u].y);
    }
  }
  for (; j + 16 <= end; j += 16) {  // 16 edges
    int s[4];
    uint2 v[4];
#pragma unroll
    for (int u = 0; u < 4; u++)
      s[u] = __builtin_nontemporal_load(&perm[j + 4 * u + sub]);
#pragma unroll
    for (int u = 0; u < 4; u++) v[u] = tab[(size_t)s[u] * 16 + cp];
#pragma unroll
    for (int u = 0; u < 4; u++) {
      a0 += bflo(v[u].x); a1 += bfhi(v[u].x);
      a2 += bflo(v[u].y); a3 += bfhi(v[u].y);
    }
  }
  for (; j + 4 <= end; j += 4) {
    int s = __builtin_nontemporal_load(&perm[j + sub]);
    uint2 v = tab[(size_t)s * 16 + cp];
    a0 += bflo(v.x); a1 += bfhi(v.x); a2 += bflo(v.y); a3 += bfhi(v.y);
  }
  if (j + sub < end) {
    int s = __builtin_nontemporal_load(&perm[j + sub]);
    uint2 v = tab[(size_t)s * 16 + cp];
    a0 += bflo(v.x); a1 += bfhi(v.x); a2 += bflo(v.y); a3 += bfhi(v.y);
  }
  a0 += __shfl_xor(a0, 16, 64); a1 += __shfl_xor(a1, 16, 64);
  a2 += __shfl_xor(a2, 16, 64); a3 += __shfl_xor(a3, 16, 64);
  a0 += __shfl_xor(a0, 32, 64); a1 += __shfl_xor(a1, 32, 64);
  a2 += __shfl_xor(a2, 32, 64); a3 += __shfl_xor(a3, 32, 64);
  if (sub == 0) {
    float dv = dinv[n];
    ((float4*)agg)[(size_t)n * 16 + cp] =
        make_float4(a0 * dv, a1 * dv, a2 * dv, a3 * dv);
  }
}

// 32-ch bf16 variant: 8 edge slots x uint2; 32-edge deep unroll.
__global__ __launch_bounds__(WG) void k_agg32b(const int* __restrict__ rowbeg,
                                               const int* __restrict__ rowend,
                                               const int* __restrict__ perm,
                                               const float* __restrict__ dinv,
                                               const uint32* __restrict__ ht,
                                               float* __restrict__ agg, int N) {
  int n = (blockIdx.x * WG + threadIdx.x) >> 6;
  int lane = threadIdx.x & 63;
  if (n >= N) return;
  const int sub = lane >> 3;   // edge slot 0..7
  const int cp = lane & 7;     // uint2 index within 64B row
  const uint2* __restrict__ tab = (const uint2*)ht;
  int beg = rowbeg[n], end = rowend[n];
  float a0 = 0.f, a1 = 0.f, a2 = 0.f, a3 = 0.f;
  if (sub == 0) {  // self-loop term
    uint2 v = tab[(size_t)n * 8 + cp];
    a0 += bflo(v.x); a1 += bfhi(v.x); a2 += bflo(v.y); a3 += bfhi(v.y);
  }
  int j = beg;
  for (; j + 32 <= end; j += 32) {  // 32 edges per iteration
    int s[4];
    uint2 v[4];
#pragma unroll
    for (int u = 0; u < 4; u++)
      s[u] = __builtin_nontemporal_load(&perm[j + 8 * u + sub]);
#pragma unroll
    for (int u = 0; u < 4; u++) v[u] = tab[(size_t)s[u] * 8 + cp];
#pragma unroll
    for (int u = 0; u < 4; u++) {
      a0 += bflo(v[u].x); a1 += bfhi(v[u].x);
      a2 += bflo(v[u].y); a3 += bfhi(v[u].y);
    }
  }
  for (; j + 16 <= end; j += 16) {  // 16 edges
    int s[2];
    uint2 v[2];
#pragma unroll
    for (int u = 0; u < 2; u++)
      s[u] = __builtin_nontemporal_load(&perm[j + 8 * u + sub]);
#pragma unroll
    for (int u = 0; u < 2; u++) v[u] = tab[(size_t)s[u] * 8 + cp];
#pragma unroll
    for (int u = 0; u < 2; u++) {
      a0 += bflo(v[u].x); a1 += bfhi(v[u].x);
      a2 += bflo(v[u].y); a3 += bfhi(v[u].y);
    }
  }
  for (; j + 8 <= end; j += 8) {
    int s = __builtin_nontemporal_load(&perm[j + sub]);
    uint2 v = tab[(size_t)s * 8 + cp];
    a0 += bflo(v.x); a1 += bfhi(v.x); a2 += bflo(v.y); a3 += bfhi(v.y);
  }
  if (j + sub < end) {
    int s = __builtin_nontemporal_load(&perm[j + sub]);
    uint2 v = tab[(size_t)s * 8 + cp];
    a0 += bflo(v.x); a1 += bfhi(v.x); a2 += bflo(v.y); a3 += bfhi(v.y);
  }
  a0 += __shfl_xor(a0, 8, 64);  a1 += __shfl_xor(a1, 8, 64);
  a2 += __shfl_xor(a2, 8, 64);  a3 += __shfl_xor(a3, 8, 64);
  a0 += __shfl_xor(a0, 16, 64); a1 += __shfl_xor(a1, 16, 64);
  a2 += __shfl_xor(a2, 16, 64); a3 += __shfl_xor(a3, 16, 64);
  a0 += __shfl_xor(a0, 32, 64); a1 += __shfl_xor(a1, 32, 64);
  a2 += __shfl_xor(a2, 32, 64); a3 += __shfl_xor(a3, 32, 64);
  if (sub == 0) {
    float dv = dinv[n];
    ((float4*)agg)[(size_t)n * 8 + cp] =
        make_float4(a0 * dv, a1 * dv, a2 * dv, a3 * dv);
  }
}

// ---------------------------------------------------------------------------
// GEMM2: ht2[n][32] = bf16( (relu(agg1[n][64] + b1) @ W2[64][32]) * dinv[n] )
// ---------------------------------------------------------------------------
__global__ __launch_bounds__(WG) void k_gemm2(const float* __restrict__ agg1,
                                              const float* __restrict__ b1,
                                              const float* __restrict__ W2,
                                              const float* __restrict__ dinv,
                                              uint32* __restrict__ ht2, int N) {
  __shared__ float as[64 * 68];
  __shared__ float w2s[64 * 32];
  const int tid = threadIdx.x;
  const int n0 = blockIdx.x * 64;

  for (int v = tid; v < 512; v += WG)
    *(float4*)&w2s[v * 4] = ((const float4*)W2)[v];
  for (int v = tid; v < 1024; v += WG) {
    int row = v >> 4, c4 = v & 15;
    int n = n0 + row;
    float4 val = make_float4(0.f, 0.f, 0.f, 0.f);
    if (n < N) {
      float4 g = ((const float4*)agg1)[(size_t)n * 16 + c4];
      float4 bb = ((const float4*)b1)[c4];
      val.x = fmaxf(g.x + bb.x, 0.f);
      val.y = fmaxf(g.y + bb.y, 0.f);
      val.z = fmaxf(g.z + bb.z, 0.f);
      val.w = fmaxf(g.w + bb.w, 0.f);
    }
    *(float4*)&as[row * 68 + c4 * 4] = val;
  }
  __syncthreads();

  const int cg = tid & 15;
  const int ng = tid >> 4;
  float acc[4][2] = {};

#pragma unroll 4
  for (int k4 = 0; k4 < 16; k4++) {
    float4 xa[4];
    float2 wv[4];
#pragma unroll
    for (int i = 0; i < 4; i++)
      xa[i] = *(const float4*)&as[(ng * 4 + i) * 68 + k4 * 4];
#pragma unroll
    for (int kk = 0; kk < 4; kk++)
      wv[kk] = *(const float2*)&w2s[(k4 * 4 + kk) * 32 + cg * 2];
#pragma unroll
    for (int i = 0; i < 4; i++) {
#pragma unroll
      for (int kk = 0; kk < 4; kk++) {
        float a = (kk == 0) ? xa[i].x : (kk == 1) ? xa[i].y : (kk == 2) ? xa[i].z : xa[i].w;
        acc[i][0] += a * wv[kk].x;
        acc[i][1] += a * wv[kk].y;
      }
    }
  }

#pragma unroll
  for (int i = 0; i < 4; i++) {
    int n = n0 + ng * 4 + i;
    if (n >= N) continue;
    float dv = dinv[n];
    ht2[(size_t)n * 16 + cg] =
        ((uint32)f2bf(acc[i][1] * dv) << 16) | f2bf(acc[i][0] * dv);
  }
}

// ---------------------------------------------------------------------------
// Final head: out[n][2] = (relu(relu(agg2[n]+b2) @ fc_w + fc_b)) @ out_w + out_b
// ---------------------------------------------------------------------------
__global__ __launch_bounds__(WG) void k_final(const float* __restrict__ agg2,
                                              const float* __restrict__ b2,
                                              const float* __restrict__ fc_w,
                                              const float* __restrict__ fc_b,
                                              const float* __restrict__ out_w,
                                              const float* __restrict__ out_b,
                                              float* __restrict__ out, int N) {
  __shared__ float hs[256 * 33];
  __shared__ float fcs[32 * 32];
  __shared__ float b2s[32], fcbs[32], ows[64];
  const int tid = threadIdx.x;
  const int n0 = blockIdx.x * 256;

  ((float4*)fcs)[tid] = ((const float4*)fc_w)[tid];
  if (tid < 32) {
    b2s[tid] = b2[tid];
    fcbs[tid] = fc_b[tid];
  }
  if (tid < 64) ows[tid] = out_w[tid];
  for (int v = tid; v < 2048; v += WG) {
    int row = v >> 3, c4 = v & 7;
    int n = n0 + row;
    float4 val = make_float4(0.f, 0.f, 0.f, 0.f);
    if (n < N) val = ((const float4*)agg2)[(size_t)n * 8 + c4];
    float* p = &hs[row * 33 + c4 * 4];
    p[0] = val.x; p[1] = val.y; p[2] = val.z; p[3] = val.w;
  }
  __syncthreads();

  int n = n0 + tid;
  float acc[32] = {};
  const int base = tid * 33;
#pragma unroll
  for (int k = 0; k < 32; k++) {
    float vk = fmaxf(hs[base + k] + b2s[k], 0.f);
#pragma unroll
    for (int j4 = 0; j4 < 8; j4++) {
      float4 f = *(const float4*)&fcs[k * 32 + j4 * 4];
      acc[j4 * 4 + 0] += vk * f.x;
      acc[j4 * 4 + 1] += vk * f.y;
      acc[j4 * 4 + 2] += vk * f.z;
      acc[j4 * 4 + 3] += vk * f.w;
    }
  }
  float o0 = out_b[0], o1 = out_b[1];
#pragma unroll
  for (int j = 0; j < 32; j++) {
    float t = fmaxf(acc[j] + fcbs[j], 0.f);
    o0 += t * ows[2 * j];
    o1 += t * ows[2 * j + 1];
  }
  if (n < N) ((float2*)out)[n] = make_float2(o0, o1);
}

// ---------------------------------------------------------------------------
extern "C" void kernel_launch(void* const* d_in, const int* in_sizes, int n_in,
                              void* d_out, int out_size, void* d_ws, size_t ws_size,
                              hipStream_t stream) {
  const float* x   = (const float*)d_in[0];
  const int*   ei  = (const int*)d_in[1];
  const float* W1  = (const float*)d_in[2];
  const float* b1  = (const float*)d_in[3];
  const float* W2  = (const float*)d_in[4];
  const float* b2  = (const float*)d_in[5];
  const float* fcw = (const float*)d_in[6];
  const float* fcb = (const float*)d_in[7];
  const float* ow  = (const float*)d_in[8];
  const float* ob  = (const float*)d_in[9];

  const int N  = in_sizes[0] / 128;
  const int E  = in_sizes[1] / 2;
  const int NB = (N + BN - 1) / BN;        // buckets (<= NBMAX)
  const int NC = (E + CHUNK - 1) / CHUNK;  // chunks
  const int CAP = (int)(((long long)E * BN) / N) + 1024;  // bucket capacity

  // workspace: cursor(NB) | pairs(NB*CAP) [agg2 aliases: dead after bsort] |
  // perm(NB*CAP) | rowbeg(N) | rowend(N) | dinv(N) | ht1(32N u32) |
  // agg1(64N f) | ht2(16N u32)
  char* p = (char*)d_ws;
  int* cursor = (int*)p;             p += ((size_t)NB + 16) * 4;
  p = (char*)(((uintptr_t)p + 63) & ~(uintptr_t)63);
  uint32* pairs = (uint32*)p;
  float* agg2 = (float*)p;           p += (size_t)NB * CAP * 4 + 64;
  int* perm = (int*)p;               p += (size_t)NB * CAP * 4 + 64;
  int* rowbeg = (int*)p;             p += (size_t)N * 4 + 64;
  int* rowend = (int*)p;             p += (size_t)N * 4 + 64;
  float* dinv = (float*)p;           p += (size_t)N * 4 + 64;
  p = (char*)(((uintptr_t)p + 63) & ~(uintptr_t)63);
  uint32* ht1 = (uint32*)p;          p += (size_t)N * 32 * 4;
  float* agg1 = (float*)p;           p += (size_t)N * 64 * 4;
  uint32* ht2 = (uint32*)p;          p += (size_t)N * 16 * 4;
  float* out = (float*)d_out;

  hipMemsetAsync(cursor, 0, (size_t)NB * sizeof(int), stream);
  hipLaunchKernelGGL(k_bin, dim3(NC), dim3(WG), 0, stream,
                     ei, cursor, pairs, NB, E, CAP);
  hipLaunchKernelGGL(k_bsort, dim3(NB), dim3(WG), 0, stream,
                     pairs, cursor, perm, rowbeg, rowend, dinv, N, CAP);
  hipLaunchKernelGGL(k_gemm1, dim3((N + 63) / 64), dim3(WG), 0, stream,
                     x, W1, dinv, ht1, N);
  {
    long long tot = (long long)N * 64;
    hipLaunchKernelGGL(k_agg64b, dim3((int)((tot + WG - 1) / WG)), dim3(WG), 0,
                       stream, rowbeg, rowend, perm, dinv, ht1, agg1, N);
  }
  hipLaunchKernelGGL(k_gemm2, dim3((N + 63) / 64), dim3(WG), 0, stream,
                     agg1, b1, W2, dinv, ht2, N);
  {
    long long tot = (long long)N * 64;
    hipLaunchKernelGGL(k_agg32b, dim3((int)((tot + WG - 1) / WG)), dim3(WG), 0,
                       stream, rowbeg, rowend, perm, dinv, ht2, agg2, N);
  }
  hipLaunchKernelGGL(k_final, dim3((N + 255) / 256), dim3(WG), 0, stream,
                     agg2, b2, fcw, fcb, ow, ob, out, N);
}

// Round 10
// 287.160 us; speedup vs baseline: 1.0435x; 1.0435x over previous
//
#include <hip/hip_runtime.h>

#define WG 256
#define BN 128        // nodes per bucket
#define NBMAX 800     // max buckets (N <= 102400)
#define CHUNK 4096    // edges per binning chunk

typedef unsigned int uint32;

__device__ inline ushort f2bf(float f) {  // fp32 -> bf16 RNE
  uint32 u = __float_as_uint(f);
  return (ushort)((u + 0x7fffu + ((u >> 16) & 1u)) >> 16);
}
__device__ inline float bflo(uint32 v) { return __uint_as_float(v << 16); }
__device__ inline float bfhi(uint32 v) { return __uint_as_float(v & 0xffff0000u); }

// int64 layout <=> all odd 32-bit words of the first 8 entries are zero.
__device__ inline bool detect_i64(const uint32* ei) {
  uint32 acc = 0;
#pragma unroll
  for (int i = 0; i < 8; i++) acc |= ei[2 * i + 1];
  return acc == 0u;
}

// ---------------------------------------------------------------------------
// Single-pass binning: per-chunk LDS histogram -> one global atomicAdd per
// (chunk,bucket) reserves a slice in [b*CAP,(b+1)*CAP) -> scatter packed
// (src<<7 | dst%BN). cursor[] pre-zeroed; afterwards cursor[b] = bucket count.
// uint4-vectorized edge loads on full chunks; scalar fallback for tail.
// ---------------------------------------------------------------------------
__global__ __launch_bounds__(WG) void k_bin(const int* __restrict__ ei,
                                            int* __restrict__ cursor,
                                            uint32* __restrict__ pairs,
                                            int NB, int E, int CAP) {
  __shared__ int hc[NBMAX];
  __shared__ int curs[NBMAX];
  const int c = blockIdx.x;
  const int t = threadIdx.x;
  for (int b = t; b < NB; b += WG) hc[b] = 0;
  __syncthreads();
  const bool i64 = detect_i64((const uint32*)ei);
  const uint32* eu = (const uint32*)ei;
  const int e0 = c * CHUNK;
  const bool full = (e0 + CHUNK <= E);

  // ---- pass 1: histogram ----
  if (full && i64 && ((E & 1) == 0)) {
    const uint4* dq = (const uint4*)(eu + 2 * (size_t)E + 2 * (size_t)e0);
    for (int i = t; i < CHUNK / 2; i += WG) {
      uint4 v = dq[i];
      atomicAdd(&hc[v.x / BN], 1);
      atomicAdd(&hc[v.z / BN], 1);
    }
  } else if (full && !i64 && ((E & 3) == 0)) {
    const uint4* dq = (const uint4*)(eu + (size_t)E + e0);
    for (int i = t; i < CHUNK / 4; i += WG) {
      uint4 v = dq[i];
      atomicAdd(&hc[v.x / BN], 1);
      atomicAdd(&hc[v.y / BN], 1);
      atomicAdd(&hc[v.z / BN], 1);
      atomicAdd(&hc[v.w / BN], 1);
    }
  } else {
    for (int i = 0; i < CHUNK; i += WG) {
      int e = e0 + i + t;
      if (e < E) {
        int d = i64 ? ei[2 * (E + (size_t)e)] : ei[E + (size_t)e];
        atomicAdd(&hc[d / BN], 1);
      }
    }
  }
  __syncthreads();

  // ---- reserve slices ----
  for (int b = t; b < NB; b += WG) {
    int cnt = hc[b];
    int base = 0;
    if (cnt > 0) base = atomicAdd(&cursor[b], cnt);
    curs[b] = b * CAP + base;
  }
  __syncthreads();

  // ---- pass 2: scatter ----
  if (full && i64 && ((E & 1) == 0)) {
    const uint4* sq = (const uint4*)(eu + 2 * (size_t)e0);
    const uint4* dq = (const uint4*)(eu + 2 * (size_t)E + 2 * (size_t)e0);
    for (int i = t; i < CHUNK / 2; i += WG) {
      uint4 sv = sq[i], dv = dq[i];
      int b0 = dv.x / BN;
      int p0 = atomicAdd(&curs[b0], 1);
      if (p0 < (b0 + 1) * CAP) pairs[p0] = (sv.x << 7) | (dv.x & (BN - 1));
      int b1 = dv.z / BN;
      int p1 = atomicAdd(&curs[b1], 1);
      if (p1 < (b1 + 1) * CAP) pairs[p1] = (sv.z << 7) | (dv.z & (BN - 1));
    }
  } else if (full && !i64 && ((E & 3) == 0)) {
    const uint4* sq = (const uint4*)(eu + e0);
    const uint4* dq = (const uint4*)(eu + (size_t)E + e0);
    for (int i = t; i < CHUNK / 4; i += WG) {
      uint4 sv = sq[i], dv = dq[i];
      uint32 ss[4] = {sv.x, sv.y, sv.z, sv.w};
      uint32 dd[4] = {dv.x, dv.y, dv.z, dv.w};
#pragma unroll
      for (int u = 0; u < 4; u++) {
        int b = dd[u] / BN;
        int pos = atomicAdd(&curs[b], 1);
        if (pos < (b + 1) * CAP) pairs[pos] = (ss[u] << 7) | (dd[u] & (BN - 1));
      }
    }
  } else {
    for (int i = 0; i < CHUNK; i += WG) {
      int e = e0 + i + t;
      if (e < E) {
        int s, d;
        if (i64) { s = ei[2 * (size_t)e]; d = ei[2 * (E + (size_t)e)]; }
        else     { s = ei[e];             d = ei[E + (size_t)e]; }
        int b = d / BN;
        int pos = atomicAdd(&curs[b], 1);
        if (pos < (b + 1) * CAP)
          pairs[pos] = ((uint32)s << 7) | (uint32)(d & (BN - 1));
      }
    }
  }
}

// ---------------------------------------------------------------------------
// Per-bucket counting sort: packed pairs -> perm (grouped per dst node),
// rowbeg/rowend, dinv. Cursors in LDS; uint4-vectorized pair sweeps
// (slices are 16B-aligned: CAP % 4 == 0 and pairs base 64B-aligned).
// ---------------------------------------------------------------------------
__global__ __launch_bounds__(WG) void k_bsort(const uint32* __restrict__ pairs,
                                              const int* __restrict__ cursor,
                                              int* __restrict__ perm,
                                              int* __restrict__ rowbeg,
                                              int* __restrict__ rowend,
                                              float* __restrict__ dinv,
                                              int N, int CAP) {
  __shared__ int cnt[BN];
  __shared__ int cur[BN];
  __shared__ int sc[BN];
  const int b = blockIdx.x;
  const int t = threadIdx.x;
  if (t < BN) cnt[t] = 0;
  __syncthreads();
  const int beg = b * CAP;
  int cb = cursor[b];
  const int m = (cb < CAP ? cb : CAP);  // edges in this bucket
  const int m4 = m >> 2;
  const uint4* pv4 = (const uint4*)(pairs + beg);

  // ---- pass 1: histogram (vectorized) ----
  for (int i = t; i < m4; i += WG) {
    uint4 v = pv4[i];
    atomicAdd(&cnt[v.x & (BN - 1)], 1);
    atomicAdd(&cnt[v.y & (BN - 1)], 1);
    atomicAdd(&cnt[v.z & (BN - 1)], 1);
    atomicAdd(&cnt[v.w & (BN - 1)], 1);
  }
  for (int e = (m4 << 2) + t; e < m; e += WG)
    atomicAdd(&cnt[pairs[beg + e] & (BN - 1)], 1);
  __syncthreads();

  // ---- scan ----
  if (t < BN) sc[t] = cnt[t];
  __syncthreads();
  for (int off = 1; off < BN; off <<= 1) {
    int v = (t < BN && t >= off) ? sc[t - off] : 0;
    __syncthreads();
    if (t < BN) sc[t] += v;
    __syncthreads();
  }
  if (t < BN) {
    int excl = beg + sc[t] - cnt[t];
    cur[t] = excl;
    int n = b * BN + t;
    if (n < N) {
      rowbeg[n] = excl;
      rowend[n] = excl + cnt[t];
      dinv[n] = rsqrtf((float)(cnt[t] + 1));  // +1 = self-loop
    }
  }
  __syncthreads();

  // ---- pass 2: scatter (vectorized loads) ----
  for (int i = t; i < m4; i += WG) {
    uint4 v = pv4[i];
    uint32 pp[4] = {v.x, v.y, v.z, v.w};
#pragma unroll
    for (int u = 0; u < 4; u++) {
      int pos = atomicAdd(&cur[pp[u] & (BN - 1)], 1);
      perm[pos] = (int)(pp[u] >> 7);
    }
  }
  for (int e = (m4 << 2) + t; e < m; e += WG) {
    uint32 p = pairs[beg + e];
    int pos = atomicAdd(&cur[p & (BN - 1)], 1);
    perm[pos] = (int)(p >> 7);
  }
}

// ---------------------------------------------------------------------------
// GEMM1: ht1[n][64] = bf16( (x[n][128] @ W1[128][64]) * dinv[n] )
// ---------------------------------------------------------------------------
__global__ __launch_bounds__(WG) void k_gemm1(const float* __restrict__ x,
                                              const float* __restrict__ W1,
                                              const float* __restrict__ dinv,
                                              uint32* __restrict__ ht1, int N) {
  __shared__ float xs[64 * 128];
  __shared__ float w1s[128 * 64];
  const int tid = threadIdx.x;
  const int n0 = blockIdx.x * 64;

  for (int v = tid; v < 2048; v += WG)
    *(float4*)&w1s[v * 4] = ((const float4*)W1)[v];
  for (int v = tid; v < 2048; v += WG) {
    int row = v >> 5, c4 = v & 31;
    int n = n0 + row;
    float4 val = make_float4(0.f, 0.f, 0.f, 0.f);
    if (n < N) val = ((const float4*)x)[(size_t)n * 32 + c4];
    *(float4*)&xs[row * 128 + ((c4 ^ ((row >> 2) & 3)) << 2)] = val;
  }
  __syncthreads();

  const int cg = tid & 15;
  const int ng = tid >> 4;
  const int ngm = ng & 3;
  float acc[4][4] = {};

#pragma unroll 4
  for (int k4 = 0; k4 < 32; k4++) {
    float4 xa[4], wv[4];
#pragma unroll
    for (int i = 0; i < 4; i++)
      xa[i] = *(const float4*)&xs[(ng * 4 + i) * 128 + ((k4 ^ ngm) << 2)];
#pragma unroll
    for (int kk = 0; kk < 4; kk++)
      wv[kk] = *(const float4*)&w1s[(k4 * 4 + kk) * 64 + cg * 4];
#pragma unroll
    for (int i = 0; i < 4; i++) {
#pragma unroll
      for (int kk = 0; kk < 4; kk++) {
        float a = (kk == 0) ? xa[i].x : (kk == 1) ? xa[i].y : (kk == 2) ? xa[i].z : xa[i].w;
        acc[i][0] += a * wv[kk].x;
        acc[i][1] += a * wv[kk].y;
        acc[i][2] += a * wv[kk].z;
        acc[i][3] += a * wv[kk].w;
      }
    }
  }

#pragma unroll
  for (int i = 0; i < 4; i++) {
    int n = n0 + ng * 4 + i;
    if (n >= N) continue;
    float dv = dinv[n];
    uint32 u01 = ((uint32)f2bf(acc[i][1] * dv) << 16) | f2bf(acc[i][0] * dv);
    uint32 u23 = ((uint32)f2bf(acc[i][3] * dv) << 16) | f2bf(acc[i][2] * dv);
    ((uint2*)ht1)[(size_t)n * 16 + cg] = make_uint2(u01, u23);
  }
}

// ---------------------------------------------------------------------------
// CSR aggregation, 64 ch bf16: wave per node; 4 edges/step x uint2 (8B/lane);
// 16-edge unroll; fp32 accumulate; xor-shuffle reduce over edge slots.
// (r8 form — the measured optimum for this phase.)
// ---------------------------------------------------------------------------
__global__ __launch_bounds__(WG) void k_agg64b(const int* __restrict__ rowbeg,
                                               const int* __restrict__ rowend,
                                               const int* __restrict__ perm,
                                               const float* __restrict__ dinv,
                                               const uint32* __restrict__ ht,
                                               float* __restrict__ agg, int N) {
  int n = (blockIdx.x * WG + threadIdx.x) >> 6;
  int lane = threadIdx.x & 63;
  if (n >= N) return;
  const int sub = lane >> 4;   // edge slot 0..3
  const int cp = lane & 15;    // uint2 index within 128B row
  const uint2* __restrict__ tab = (const uint2*)ht;
  int beg = rowbeg[n], end = rowend[n];
  float a0 = 0.f, a1 = 0.f, a2 = 0.f, a3 = 0.f;
  if (sub == 0) {  // self-loop term
    uint2 v = tab[(size_t)n * 16 + cp];
    a0 += bflo(v.x); a1 += bfhi(v.x); a2 += bflo(v.y); a3 += bfhi(v.y);
  }
  int j = beg;
  for (; j + 16 <= end; j += 16) {  // 16 edges per iteration
    int s[4];
    uint2 v[4];
#pragma unroll
    for (int u = 0; u < 4; u++) s[u] = perm[j + 4 * u + sub];
#pragma unroll
    for (int u = 0; u < 4; u++) v[u] = tab[(size_t)s[u] * 16 + cp];
#pragma unroll
    for (int u = 0; u < 4; u++) {
      a0 += bflo(v[u].x); a1 += bfhi(v[u].x);
      a2 += bflo(v[u].y); a3 += bfhi(v[u].y);
    }
  }
  for (; j + 4 <= end; j += 4) {
    int s = perm[j + sub];
    uint2 v = tab[(size_t)s * 16 + cp];
    a0 += bflo(v.x); a1 += bfhi(v.x); a2 += bflo(v.y); a3 += bfhi(v.y);
  }
  if (j + sub < end) {
    int s = perm[j + sub];
    uint2 v = tab[(size_t)s * 16 + cp];
    a0 += bflo(v.x); a1 += bfhi(v.x); a2 += bflo(v.y); a3 += bfhi(v.y);
  }
  a0 += __shfl_xor(a0, 16, 64); a1 += __shfl_xor(a1, 16, 64);
  a2 += __shfl_xor(a2, 16, 64); a3 += __shfl_xor(a3, 16, 64);
  a0 += __shfl_xor(a0, 32, 64); a1 += __shfl_xor(a1, 32, 64);
  a2 += __shfl_xor(a2, 32, 64); a3 += __shfl_xor(a3, 32, 64);
  if (sub == 0) {
    float dv = dinv[n];
    ((float4*)agg)[(size_t)n * 16 + cp] =
        make_float4(a0 * dv, a1 * dv, a2 * dv, a3 * dv);
  }
}

// 32-ch bf16 variant: 8 edges/step x uint2 (64B row), 16-edge unroll.
__global__ __launch_bounds__(WG) void k_agg32b(const int* __restrict__ rowbeg,
                                               const int* __restrict__ rowend,
                                               const int* __restrict__ perm,
                                               const float* __restrict__ dinv,
                                               const uint32* __restrict__ ht,
                                               float* __restrict__ agg, int N) {
  int n = (blockIdx.x * WG + threadIdx.x) >> 6;
  int lane = threadIdx.x & 63;
  if (n >= N) return;
  const int sub = lane >> 3;   // edge slot 0..7
  const int cp = lane & 7;     // uint2 index within 64B row
  const uint2* __restrict__ tab = (const uint2*)ht;
  int beg = rowbeg[n], end = rowend[n];
  float a0 = 0.f, a1 = 0.f, a2 = 0.f, a3 = 0.f;
  if (sub == 0) {  // self-loop term
    uint2 v = tab[(size_t)n * 8 + cp];
    a0 += bflo(v.x); a1 += bfhi(v.x); a2 += bflo(v.y); a3 += bfhi(v.y);
  }
  int j = beg;
  for (; j + 16 <= end; j += 16) {  // 16 edges per iteration
    int s[2];
    uint2 v[2];
#pragma unroll
    for (int u = 0; u < 2; u++) s[u] = perm[j + 8 * u + sub];
#pragma unroll
    for (int u = 0; u < 2; u++) v[u] = tab[(size_t)s[u] * 8 + cp];
#pragma unroll
    for (int u = 0; u < 2; u++) {
      a0 += bflo(v[u].x); a1 += bfhi(v[u].x);
      a2 += bflo(v[u].y); a3 += bfhi(v[u].y);
    }
  }
  for (; j + 8 <= end; j += 8) {
    int s = perm[j + sub];
    uint2 v = tab[(size_t)s * 8 + cp];
    a0 += bflo(v.x); a1 += bfhi(v.x); a2 += bflo(v.y); a3 += bfhi(v.y);
  }
  if (j + sub < end) {
    int s = perm[j + sub];
    uint2 v = tab[(size_t)s * 8 + cp];
    a0 += bflo(v.x); a1 += bfhi(v.x); a2 += bflo(v.y); a3 += bfhi(v.y);
  }
  a0 += __shfl_xor(a0, 8, 64);  a1 += __shfl_xor(a1, 8, 64);
  a2 += __shfl_xor(a2, 8, 64);  a3 += __shfl_xor(a3, 8, 64);
  a0 += __shfl_xor(a0, 16, 64); a1 += __shfl_xor(a1, 16, 64);
  a2 += __shfl_xor(a2, 16, 64); a3 += __shfl_xor(a3, 16, 64);
  a0 += __shfl_xor(a0, 32, 64); a1 += __shfl_xor(a1, 32, 64);
  a2 += __shfl_xor(a2, 32, 64); a3 += __shfl_xor(a3, 32, 64);
  if (sub == 0) {
    float dv = dinv[n];
    ((float4*)agg)[(size_t)n * 8 + cp] =
        make_float4(a0 * dv, a1 * dv, a2 * dv, a3 * dv);
  }
}

// ---------------------------------------------------------------------------
// GEMM2: ht2[n][32] = bf16( (relu(agg1[n][64] + b1) @ W2[64][32]) * dinv[n] )
// ---------------------------------------------------------------------------
__global__ __launch_bounds__(WG) void k_gemm2(const float* __restrict__ agg1,
                                              const float* __restrict__ b1,
                                              const float* __restrict__ W2,
                                              const float* __restrict__ dinv,
                                              uint32* __restrict__ ht2, int N) {
  __shared__ float as[64 * 68];
  __shared__ float w2s[64 * 32];
  const int tid = threadIdx.x;
  const int n0 = blockIdx.x * 64;

  for (int v = tid; v < 512; v += WG)
    *(float4*)&w2s[v * 4] = ((const float4*)W2)[v];
  for (int v = tid; v < 1024; v += WG) {
    int row = v >> 4, c4 = v & 15;
    int n = n0 + row;
    float4 val = make_float4(0.f, 0.f, 0.f, 0.f);
    if (n < N) {
      float4 g = ((const float4*)agg1)[(size_t)n * 16 + c4];
      float4 bb = ((const float4*)b1)[c4];
      val.x = fmaxf(g.x + bb.x, 0.f);
      val.y = fmaxf(g.y + bb.y, 0.f);
      val.z = fmaxf(g.z + bb.z, 0.f);
      val.w = fmaxf(g.w + bb.w, 0.f);
    }
    *(float4*)&as[row * 68 + c4 * 4] = val;
  }
  __syncthreads();

  const int cg = tid & 15;
  const int ng = tid >> 4;
  float acc[4][2] = {};

#pragma unroll 4
  for (int k4 = 0; k4 < 16; k4++) {
    float4 xa[4];
    float2 wv[4];
#pragma unroll
    for (int i = 0; i < 4; i++)
      xa[i] = *(const float4*)&as[(ng * 4 + i) * 68 + k4 * 4];
#pragma unroll
    for (int kk = 0; kk < 4; kk++)
      wv[kk] = *(const float2*)&w2s[(k4 * 4 + kk) * 32 + cg * 2];
#pragma unroll
    for (int i = 0; i < 4; i++) {
#pragma unroll
      for (int kk = 0; kk < 4; kk++) {
        float a = (kk == 0) ? xa[i].x : (kk == 1) ? xa[i].y : (kk == 2) ? xa[i].z : xa[i].w;
        acc[i][0] += a * wv[kk].x;
        acc[i][1] += a * wv[kk].y;
      }
    }
  }

#pragma unroll
  for (int i = 0; i < 4; i++) {
    int n = n0 + ng * 4 + i;
    if (n >= N) continue;
    float dv = dinv[n];
    ht2[(size_t)n * 16 + cg] =
        ((uint32)f2bf(acc[i][1] * dv) << 16) | f2bf(acc[i][0] * dv);
  }
}

// ---------------------------------------------------------------------------
// Final head: out[n][2] = (relu(relu(agg2[n]+b2) @ fc_w + fc_b)) @ out_w + out_b
// ---------------------------------------------------------------------------
__global__ __launch_bounds__(WG) void k_final(const float* __restrict__ agg2,
                                              const float* __restrict__ b2,
                                              const float* __restrict__ fc_w,
                                              const float* __restrict__ fc_b,
                                              const float* __restrict__ out_w,
                                              const float* __restrict__ out_b,
                                              float* __restrict__ out, int N) {
  __shared__ float hs[256 * 33];
  __shared__ float fcs[32 * 32];
  __shared__ float b2s[32], fcbs[32], ows[64];
  const int tid = threadIdx.x;
  const int n0 = blockIdx.x * 256;

  ((float4*)fcs)[tid] = ((const float4*)fc_w)[tid];
  if (tid < 32) {
    b2s[tid] = b2[tid];
    fcbs[tid] = fc_b[tid];
  }
  if (tid < 64) ows[tid] = out_w[tid];
  for (int v = tid; v < 2048; v += WG) {
    int row = v >> 3, c4 = v & 7;
    int n = n0 + row;
    float4 val = make_float4(0.f, 0.f, 0.f, 0.f);
    if (n < N) val = ((const float4*)agg2)[(size_t)n * 8 + c4];
    float* p = &hs[row * 33 + c4 * 4];
    p[0] = val.x; p[1] = val.y; p[2] = val.z; p[3] = val.w;
  }
  __syncthreads();

  int n = n0 + tid;
  float acc[32] = {};
  const int base = tid * 33;
#pragma unroll
  for (int k = 0; k < 32; k++) {
    float vk = fmaxf(hs[base + k] + b2s[k], 0.f);
#pragma unroll
    for (int j4 = 0; j4 < 8; j4++) {
      float4 f = *(const float4*)&fcs[k * 32 + j4 * 4];
      acc[j4 * 4 + 0] += vk * f.x;
      acc[j4 * 4 + 1] += vk * f.y;
      acc[j4 * 4 + 2] += vk * f.z;
      acc[j4 * 4 + 3] += vk * f.w;
    }
  }
  float o0 = out_b[0], o1 = out_b[1];
#pragma unroll
  for (int j = 0; j < 32; j++) {
    float t = fmaxf(acc[j] + fcbs[j], 0.f);
    o0 += t * ows[2 * j];
    o1 += t * ows[2 * j + 1];
  }
  if (n < N) ((float2*)out)[n] = make_float2(o0, o1);
}

// ---------------------------------------------------------------------------
extern "C" void kernel_launch(void* const* d_in, const int* in_sizes, int n_in,
                              void* d_out, int out_size, void* d_ws, size_t ws_size,
                              hipStream_t stream) {
  const float* x   = (const float*)d_in[0];
  const int*   ei  = (const int*)d_in[1];
  const float* W1  = (const float*)d_in[2];
  const float* b1  = (const float*)d_in[3];
  const float* W2  = (const float*)d_in[4];
  const float* b2  = (const float*)d_in[5];
  const float* fcw = (const float*)d_in[6];
  const float* fcb = (const float*)d_in[7];
  const float* ow  = (const float*)d_in[8];
  const float* ob  = (const float*)d_in[9];

  const int N  = in_sizes[0] / 128;
  const int E  = in_sizes[1] / 2;
  const int NB = (N + BN - 1) / BN;        // buckets (<= NBMAX)
  const int NC = (E + CHUNK - 1) / CHUNK;  // chunks
  int CAP = (int)(((long long)E * BN) / N) + 1024;  // bucket capacity
  CAP = (CAP + 3) & ~3;                    // keep slices 16B-aligned

  // workspace: cursor(NB) | pairs(NB*CAP) [agg2 aliases: dead after bsort] |
  // perm(NB*CAP) | rowbeg(N) | rowend(N) | dinv(N) | ht1(32N u32) |
  // agg1(64N f) | ht2(16N u32)
  char* p = (char*)d_ws;
  int* cursor = (int*)p;             p += ((size_t)NB + 16) * 4;
  p = (char*)(((uintptr_t)p + 63) & ~(uintptr_t)63);
  uint32* pairs = (uint32*)p;
  float* agg2 = (float*)p;           p += (size_t)NB * CAP * 4 + 64;
  p = (char*)(((uintptr_t)p + 63) & ~(uintptr_t)63);
  int* perm = (int*)p;               p += (size_t)NB * CAP * 4 + 64;
  int* rowbeg = (int*)p;             p += (size_t)N * 4 + 64;
  int* rowend = (int*)p;             p += (size_t)N * 4 + 64;
  float* dinv = (float*)p;           p += (size_t)N * 4 + 64;
  p = (char*)(((uintptr_t)p + 63) & ~(uintptr_t)63);
  uint32* ht1 = (uint32*)p;          p += (size_t)N * 32 * 4;
  float* agg1 = (float*)p;           p += (size_t)N * 64 * 4;
  uint32* ht2 = (uint32*)p;          p += (size_t)N * 16 * 4;
  float* out = (float*)d_out;

  hipMemsetAsync(cursor, 0, (size_t)NB * sizeof(int), stream);
  hipLaunchKernelGGL(k_bin, dim3(NC), dim3(WG), 0, stream,
                     ei, cursor, pairs, NB, E, CAP);
  hipLaunchKernelGGL(k_bsort, dim3(NB), dim3(WG), 0, stream,
                     pairs, cursor, perm, rowbeg, rowend, dinv, N, CAP);
  hipLaunchKernelGGL(k_gemm1, dim3((N + 63) / 64), dim3(WG), 0, stream,
                     x, W1, dinv, ht1, N);
  {
    long long tot = (long long)N * 64;
    hipLaunchKernelGGL(k_agg64b, dim3((int)((tot + WG - 1) / WG)), dim3(WG), 0,
                       stream, rowbeg, rowend, perm, dinv, ht1, agg1, N);
  }
  hipLaunchKernelGGL(k_gemm2, dim3((N + 63) / 64), dim3(WG), 0, stream,
                     agg1, b1, W2, dinv, ht2, N);
  {
    long long tot = (long long)N * 64;
    hipLaunchKernelGGL(k_agg32b, dim3((int)((tot + WG - 1) / WG)), dim3(WG), 0,
                       stream, rowbeg, rowend, perm, dinv, ht2, agg2, N);
  }
  hipLaunchKernelGGL(k_final, dim3((N + 255) / 256), dim3(WG), 0, stream,
                     agg2, b2, fcw, fcb, ow, ob, out, N);
}